// Round 1
// baseline (8803.556 us; speedup 1.0000x reference)
//
#include <hip/hip_runtime.h>
#include <cstdint>

#define T_STEPS 1024
#define BATCH   32
#define DIM     1024
#define RANK    128
#define BD      (BATCH*DIM)            // 32768
#define TBD     ((size_t)T_STEPS*BD)   // 33554432

typedef _Float16 half2v __attribute__((ext_vector_type(2)));

__device__ __forceinline__ float dot2f(uint32_t a, uint32_t b, float acc) {
#if __has_builtin(__builtin_amdgcn_fdot2)
  return __builtin_amdgcn_fdot2(__builtin_bit_cast(half2v, a),
                                __builtin_bit_cast(half2v, b), acc, false);
#else
  half2v xx = __builtin_bit_cast(half2v, a);
  half2v yy = __builtin_bit_cast(half2v, b);
  return acc + (float)xx[0]*(float)yy[0] + (float)xx[1]*(float)yy[1];
#endif
}

__device__ __forceinline__ uint16_t f16b(float x) {
  _Float16 h = (_Float16)x;
  return __builtin_bit_cast(unsigned short, h);
}
__device__ __forceinline__ uint32_t pack2(float a, float b) {
  return (uint32_t)f16b(a) | ((uint32_t)f16b(b) << 16);
}
__device__ __forceinline__ float fast_tanh(float x) {
  float e = __expf(2.0f*x);
  return 1.0f - 2.0f/(e + 1.0f);
}
__device__ __forceinline__ float fast_silu(float zz) {
  return zz / (1.0f + __expf(-zz));
}

// ---------------------------------------------------------------------------
// K0: pack weights to f16 pairs in ws (s_h folded into U_h, s_x into U_x),
// and copy h0 into h-slot 0 of the output.
// ws layout (uint32 words): [0]     vhw [128][512]
//                           [65536] uhw [1024][64]
//                           [131072] vxw [128][512]
//                           [196608] uxw [1024][64]
// ---------------------------------------------------------------------------
__global__ void prep_kernel(const float* __restrict__ Uh, const float* __restrict__ Vh,
                            const float* __restrict__ sh, const float* __restrict__ Ux,
                            const float* __restrict__ Vx, const float* __restrict__ sx,
                            const float* __restrict__ h0, uint32_t* __restrict__ ws32,
                            float* __restrict__ hout) {
  int i = blockIdx.x*blockDim.x + threadIdx.x;
  int n = gridDim.x*blockDim.x;
  for (int p = i; p < 65536; p += n) {
    int r = p >> 9, dp = p & 511;
    ws32[p] = pack2(Vh[r*1024 + 2*dp], Vh[r*1024 + 2*dp + 1]);
  }
  for (int p = i; p < 65536; p += n) {
    int d = p >> 6, rp = p & 63;
    ws32[65536 + p] = pack2(Uh[d*128 + 2*rp]   * sh[2*rp],
                            Uh[d*128 + 2*rp+1] * sh[2*rp+1]);
  }
  for (int p = i; p < 65536; p += n) {
    int r = p >> 9, dp = p & 511;
    ws32[131072 + p] = pack2(Vx[r*1024 + 2*dp], Vx[r*1024 + 2*dp + 1]);
  }
  for (int p = i; p < 65536; p += n) {
    int d = p >> 6, rp = p & 63;
    ws32[196608 + p] = pack2(Ux[d*128 + 2*rp]   * sx[2*rp],
                             Ux[d*128 + 2*rp+1] * sx[2*rp+1]);
  }
  for (int p = i; p < BD; p += n) hout[p] = h0[p];
}

// ---------------------------------------------------------------------------
// K1: input branch. One WG per timestep t.
// c[t,b,d] = sum_r U'_x[d,r] * (sum_d' V_x[r,d'] * x[t,b,d']) + bias[d]
// written (f32) into h-slot (t+1) of the output; recurrence overwrites with h.
// ---------------------------------------------------------------------------
__global__ __launch_bounds__(512, 4) void inp_kernel(
    const float* __restrict__ x, const uint32_t* __restrict__ ws32,
    const float* __restrict__ bias, float* __restrict__ hout) {
  const int t = blockIdx.x;
  const int l = threadIdx.x;  // 0..511
  __shared__ __attribute__((aligned(16))) uint32_t xs[32*516];      // x_t as f16 pairs, padded rows
  __shared__ __attribute__((aligned(16))) uint16_t svx[BATCH*RANK]; // Vx f16

  // stage x_t -> LDS f16 pairs
  const float4* xg = (const float4*)(x + (size_t)t*BD);
  #pragma unroll
  for (int k = 0; k < 16; k++) {
    int i = l + 512*k;              // float4 index 0..8191
    float4 v = xg[i];
    int bb = i >> 8;                // 256 float4 per row of 1024
    int d4 = i & 255;
    xs[bb*516 + d4*2]     = pack2(v.x, v.y);
    xs[bb*516 + d4*2 + 1] = pack2(v.z, v.w);
  }
  __syncthreads();

  // GEMM1: Vx[b][r], lane -> (r = l&127, 8 b's via bq = l>>7)
  const int r  = l & 127;
  const int bq = l >> 7;
  const uint4* wrow = (const uint4*)(ws32 + 131072 + r*512);
  float acc0[8], acc1[8];
  #pragma unroll
  for (int bi = 0; bi < 8; bi++) { acc0[bi] = 0.f; acc1[bi] = 0.f; }
  #pragma unroll 4
  for (int J = 0; J < 128; J += 2) {
    uint4 w0 = wrow[J];
    uint4 w1 = wrow[J+1];
    #pragma unroll
    for (int bi = 0; bi < 8; bi++) {
      const uint4* xrow = (const uint4*)(xs + (bq*8+bi)*516);
      uint4 h0v = xrow[J];
      acc0[bi] = dot2f(w0.x, h0v.x, acc0[bi]);
      acc0[bi] = dot2f(w0.y, h0v.y, acc0[bi]);
      acc0[bi] = dot2f(w0.z, h0v.z, acc0[bi]);
      acc0[bi] = dot2f(w0.w, h0v.w, acc0[bi]);
      uint4 h1v = xrow[J+1];
      acc1[bi] = dot2f(w1.x, h1v.x, acc1[bi]);
      acc1[bi] = dot2f(w1.y, h1v.y, acc1[bi]);
      acc1[bi] = dot2f(w1.z, h1v.z, acc1[bi]);
      acc1[bi] = dot2f(w1.w, h1v.w, acc1[bi]);
    }
  }
  #pragma unroll
  for (int bi = 0; bi < 8; bi++)
    svx[(bq*8+bi)*RANK + r] = f16b(acc0[bi] + acc1[bi]);
  __syncthreads();

  // GEMM2: Ux[b][d] + bias, lane -> d = l and l+512
  const uint4* svx4 = (const uint4*)svx;   // row stride 16 uint4 per b
  float accb[BATCH];
  #pragma unroll 1
  for (int dd = 0; dd < 2; dd++) {
    int d = l + dd*512;
    const uint4* urow = (const uint4*)(ws32 + 196608 + d*64);
    #pragma unroll
    for (int bi = 0; bi < BATCH; bi++) accb[bi] = 0.f;
    #pragma unroll
    for (int RP = 0; RP < 16; RP++) {
      uint4 w = urow[RP];
      #pragma unroll
      for (int bi = 0; bi < BATCH; bi++) {
        uint4 sv = svx4[bi*16 + RP];
        accb[bi] = dot2f(w.x, sv.x, accb[bi]);
        accb[bi] = dot2f(w.y, sv.y, accb[bi]);
        accb[bi] = dot2f(w.z, sv.z, accb[bi]);
        accb[bi] = dot2f(w.w, sv.w, accb[bi]);
      }
    }
    float bv = bias[d];
    float* cslot = hout + (size_t)(t+1)*BD + d;
    #pragma unroll
    for (int bi = 0; bi < BATCH; bi++)
      cslot[(size_t)bi*DIM] = accb[bi] + bv;
  }
}

// ---------------------------------------------------------------------------
// K2: recurrence. One WG (256 threads, 1 CU) per batch element; no cross-WG
// sync. Weights resident: V_h rows 0..63 in LDS (padded stride 516 words,
// bank-optimal for b128), V_h rows 64..127 + all of U'_h in VGPRs
// (384 VGPRs/lane of weights; __launch_bounds__(256,1) -> 512-VGPR budget).
// Per step: phase A (Vh matvec, 4-lane split over D + shfl reduce),
// barrier, phase B (Uh matvec from reg weights, tanh, fused silu epilogue,
// h written both to global f32 and LDS f16 pairs), barrier.
// ---------------------------------------------------------------------------
__global__ __launch_bounds__(256, 1) void rec_kernel(
    const uint32_t* __restrict__ ws32, const float* __restrict__ z,
    float* __restrict__ outb) {
  const int b = blockIdx.x;
  const int l = threadIdx.x;
  float* hout = outb + TBD;
  const uint32_t* vhw = ws32;
  const uint32_t* uhw = ws32 + 65536;

  __shared__ __attribute__((aligned(16))) uint32_t vlds[64*516]; // 132 KB
  __shared__ __attribute__((aligned(16))) uint32_t hsw[512];     // h as f16 pairs
  __shared__ __attribute__((aligned(16))) uint32_t svh[64];      // Vh as f16 pairs

  // V_h rows 0..63 -> LDS (row stride 516 words)
  for (int i = l; i < 64*512; i += 256) {
    int rr = i >> 9, dp = i & 511;
    vlds[rr*516 + dp] = vhw[rr*512 + dp];
  }
  const int rl  = l >> 2;   // 0..63
  const int dpc = l & 3;    // 0..3 : D-pair window dpc*128..+127

  // V_h rows 64..127 -> regs (128 VGPRs)
  uint4 vq[32];
  {
    const uint4* src = (const uint4*)(vhw + (64 + rl)*512 + dpc*128);
    #pragma unroll
    for (int J = 0; J < 32; J++) vq[J] = src[J];
  }
  // U'_h rows d = l + 256k -> regs (256 VGPRs)
  uint4 uq[4][16];
  #pragma unroll
  for (int k = 0; k < 4; k++) {
    const uint4* src = (const uint4*)(uhw + (l + 256*k)*64);
    #pragma unroll
    for (int J = 0; J < 16; J++) uq[k][J] = src[J];
  }
  // init h LDS from h-slot 0 (h0, written by prep_kernel)
  {
    const float2* h0p = (const float2*)(hout + b*DIM);
    for (int p = l; p < 512; p += 256) {
      float2 v = h0p[p];
      hsw[p] = pack2(v.x, v.y);
    }
  }
  __syncthreads();

  const uint4* hs4  = (const uint4*)hsw;
  const uint4* vl4  = (const uint4*)vlds;
  const uint4* svh4 = (const uint4*)svh;

  const float* zp = z + b*DIM;
  float*       cp = hout + BD + b*DIM;   // slot t+1 (holds c, overwritten with h)
  float*       op = outb + b*DIM;

  for (int t = 0; t < T_STEPS; t++) {
    // ---- phase A: Vh[r] partials over this lane's 128 d-pairs ----
    float aL0=0.f, aL1=0.f, aR0=0.f, aR1=0.f;
    const uint4* vlrow = vl4 + rl*129 + dpc*32;
    const uint4* hrow  = hs4 + dpc*32;
    #pragma unroll
    for (int J = 0; J < 32; J += 2) {
      uint4 hv0 = hrow[J];
      uint4 wl0 = vlrow[J];
      uint4 wr0 = vq[J];
      uint4 hv1 = hrow[J+1];
      uint4 wl1 = vlrow[J+1];
      uint4 wr1 = vq[J+1];
      aL0 = dot2f(wl0.x, hv0.x, aL0); aL0 = dot2f(wl0.y, hv0.y, aL0);
      aL0 = dot2f(wl0.z, hv0.z, aL0); aL0 = dot2f(wl0.w, hv0.w, aL0);
      aR0 = dot2f(wr0.x, hv0.x, aR0); aR0 = dot2f(wr0.y, hv0.y, aR0);
      aR0 = dot2f(wr0.z, hv0.z, aR0); aR0 = dot2f(wr0.w, hv0.w, aR0);
      aL1 = dot2f(wl1.x, hv1.x, aL1); aL1 = dot2f(wl1.y, hv1.y, aL1);
      aL1 = dot2f(wl1.z, hv1.z, aL1); aL1 = dot2f(wl1.w, hv1.w, aL1);
      aR1 = dot2f(wr1.x, hv1.x, aR1); aR1 = dot2f(wr1.y, hv1.y, aR1);
      aR1 = dot2f(wr1.z, hv1.z, aR1); aR1 = dot2f(wr1.w, hv1.w, aR1);
    }
    float aL = aL0 + aL1, aR = aR0 + aR1;
    aL += __shfl_xor(aL, 1); aL += __shfl_xor(aL, 2);
    aR += __shfl_xor(aR, 1); aR += __shfl_xor(aR, 2);
    if (dpc == 0) {
      ((uint16_t*)svh)[rl]      = f16b(aL);   // Vh[rl]
      ((uint16_t*)svh)[64 + rl] = f16b(aR);   // Vh[64+rl]
    }
    __syncthreads();

    // ---- phase B: Uh[d] for d = l+256k, tanh, epilogue ----
    #pragma unroll
    for (int k = 0; k < 4; k++) {
      int d = l + 256*k;
      float a0 = 0.f, a1 = 0.f;
      #pragma unroll
      for (int RP = 0; RP < 16; RP += 2) {
        uint4 sv0 = svh4[RP];
        uint4 w0  = uq[k][RP];
        uint4 sv1 = svh4[RP+1];
        uint4 w1  = uq[k][RP+1];
        a0 = dot2f(w0.x, sv0.x, a0); a0 = dot2f(w0.y, sv0.y, a0);
        a0 = dot2f(w0.z, sv0.z, a0); a0 = dot2f(w0.w, sv0.w, a0);
        a1 = dot2f(w1.x, sv1.x, a1); a1 = dot2f(w1.y, sv1.y, a1);
        a1 = dot2f(w1.z, sv1.z, a1); a1 = dot2f(w1.w, sv1.w, a1);
      }
      float cc = cp[d];                 // c = Ux + bias
      float hv = fast_tanh(a0 + a1 + cc);
      cp[d] = hv;                       // h[t+1] (f32, final output)
      ((uint16_t*)hsw)[d] = f16b(hv);   // h for next step (f16)
      float zz = zp[d];
      op[d] = hv * fast_silu(zz);       // out[t]
    }
    __syncthreads();

    cp += BD; zp += BD; op += BD;
  }
}

extern "C" void kernel_launch(void* const* d_in, const int* in_sizes, int n_in,
                              void* d_out, int out_size, void* d_ws, size_t ws_size,
                              hipStream_t stream) {
  const float* x  = (const float*)d_in[0];
  const float* z  = (const float*)d_in[1];
  const float* h0 = (const float*)d_in[2];
  const float* Uh = (const float*)d_in[3];
  const float* Vh = (const float*)d_in[4];
  const float* sh = (const float*)d_in[5];
  const float* Ux = (const float*)d_in[6];
  const float* Vx = (const float*)d_in[7];
  const float* sx = (const float*)d_in[8];
  const float* bb = (const float*)d_in[9];
  float* outb = (float*)d_out;
  uint32_t* ws32 = (uint32_t*)d_ws;   // needs 1 MiB

  prep_kernel<<<512, 256, 0, stream>>>(Uh, Vh, sh, Ux, Vx, sx, h0, ws32, outb + TBD);
  inp_kernel<<<T_STEPS, 512, 0, stream>>>(x, ws32, bb, outb + TBD);
  rec_kernel<<<BATCH, 256, 0, stream>>>(ws32, z, outb);
}

// Round 2
// 3597.747 us; speedup vs baseline: 2.4470x; 2.4470x over previous
//
#include <hip/hip_runtime.h>
#include <cstdint>

#define T_STEPS 1024
#define BATCH   32
#define DIM     1024
#define RANK    128
#define BD      (BATCH*DIM)            // 32768
#define TBD     ((size_t)T_STEPS*BD)   // 33554432

typedef _Float16 half2v __attribute__((ext_vector_type(2)));

__device__ __forceinline__ float dot2f(uint32_t a, uint32_t b, float acc) {
#if __has_builtin(__builtin_amdgcn_fdot2)
  return __builtin_amdgcn_fdot2(__builtin_bit_cast(half2v, a),
                                __builtin_bit_cast(half2v, b), acc, false);
#else
  half2v xx = __builtin_bit_cast(half2v, a);
  half2v yy = __builtin_bit_cast(half2v, b);
  return acc + (float)xx[0]*(float)yy[0] + (float)xx[1]*(float)yy[1];
#endif
}

__device__ __forceinline__ uint16_t f16b(float x) {
  _Float16 h = (_Float16)x;
  return __builtin_bit_cast(unsigned short, h);
}
__device__ __forceinline__ uint32_t pack2(float a, float b) {
  return (uint32_t)f16b(a) | ((uint32_t)f16b(b) << 16);
}
__device__ __forceinline__ float fast_tanh(float x) {
  float e = __expf(2.0f*x);
  return 1.0f - 2.0f/(e + 1.0f);
}
__device__ __forceinline__ float fast_silu(float zz) {
  return zz / (1.0f + __expf(-zz));
}

// barrier that does NOT drain vmcnt: only LDS ordering is required between
// phases (no cross-lane global-memory dependencies exist in rec_kernel).
__device__ __forceinline__ void lds_barrier() {
  asm volatile("s_waitcnt lgkmcnt(0)" ::: "memory");
  __builtin_amdgcn_s_barrier();
  __builtin_amdgcn_sched_barrier(0);
}

// ---------------------------------------------------------------------------
// K0: pack weights to f16 pairs in ws (s_h folded into U_h, s_x into U_x),
// and copy h0 into h-slot 0 of the output.
// ws layout (uint32 words): [0]      vhw [128][512]
//                           [65536]  uhw [1024][64]
//                           [131072] vxw [128][512]
//                           [196608] uxw [1024][64]
// ---------------------------------------------------------------------------
__global__ void prep_kernel(const float* __restrict__ Uh, const float* __restrict__ Vh,
                            const float* __restrict__ sh, const float* __restrict__ Ux,
                            const float* __restrict__ Vx, const float* __restrict__ sx,
                            const float* __restrict__ h0, uint32_t* __restrict__ ws32,
                            float* __restrict__ hout) {
  int i = blockIdx.x*blockDim.x + threadIdx.x;
  int n = gridDim.x*blockDim.x;
  for (int p = i; p < 65536; p += n) {
    int r = p >> 9, dp = p & 511;
    ws32[p] = pack2(Vh[r*1024 + 2*dp], Vh[r*1024 + 2*dp + 1]);
  }
  for (int p = i; p < 65536; p += n) {
    int d = p >> 6, rp = p & 63;
    ws32[65536 + p] = pack2(Uh[d*128 + 2*rp]   * sh[2*rp],
                            Uh[d*128 + 2*rp+1] * sh[2*rp+1]);
  }
  for (int p = i; p < 65536; p += n) {
    int r = p >> 9, dp = p & 511;
    ws32[131072 + p] = pack2(Vx[r*1024 + 2*dp], Vx[r*1024 + 2*dp + 1]);
  }
  for (int p = i; p < 65536; p += n) {
    int d = p >> 6, rp = p & 63;
    ws32[196608 + p] = pack2(Ux[d*128 + 2*rp]   * sx[2*rp],
                             Ux[d*128 + 2*rp+1] * sx[2*rp+1]);
  }
  for (int p = i; p < BD; p += n) hout[p] = h0[p];
}

// ---------------------------------------------------------------------------
// K1: input branch. One WG per timestep t.  (unchanged from round 1)
// c[t,b,d] = sum_r U'_x[d,r] * (sum_d' V_x[r,d'] * x[t,b,d']) + bias[d]
// written (f32) into h-slot (t+1) of the output; recurrence overwrites with h.
// ---------------------------------------------------------------------------
__global__ __launch_bounds__(512, 4) void inp_kernel(
    const float* __restrict__ x, const uint32_t* __restrict__ ws32,
    const float* __restrict__ bias, float* __restrict__ hout) {
  const int t = blockIdx.x;
  const int l = threadIdx.x;  // 0..511
  __shared__ __attribute__((aligned(16))) uint32_t xs[32*516];
  __shared__ __attribute__((aligned(16))) uint16_t svx[BATCH*RANK];

  const float4* xg = (const float4*)(x + (size_t)t*BD);
  #pragma unroll
  for (int k = 0; k < 16; k++) {
    int i = l + 512*k;
    float4 v = xg[i];
    int bb = i >> 8;
    int d4 = i & 255;
    xs[bb*516 + d4*2]     = pack2(v.x, v.y);
    xs[bb*516 + d4*2 + 1] = pack2(v.z, v.w);
  }
  __syncthreads();

  const int r  = l & 127;
  const int bq = l >> 7;
  const uint4* wrow = (const uint4*)(ws32 + 131072 + r*512);
  float acc0[8], acc1[8];
  #pragma unroll
  for (int bi = 0; bi < 8; bi++) { acc0[bi] = 0.f; acc1[bi] = 0.f; }
  #pragma unroll 4
  for (int J = 0; J < 128; J += 2) {
    uint4 w0 = wrow[J];
    uint4 w1 = wrow[J+1];
    #pragma unroll
    for (int bi = 0; bi < 8; bi++) {
      const uint4* xrow = (const uint4*)(xs + (bq*8+bi)*516);
      uint4 h0v = xrow[J];
      acc0[bi] = dot2f(w0.x, h0v.x, acc0[bi]);
      acc0[bi] = dot2f(w0.y, h0v.y, acc0[bi]);
      acc0[bi] = dot2f(w0.z, h0v.z, acc0[bi]);
      acc0[bi] = dot2f(w0.w, h0v.w, acc0[bi]);
      uint4 h1v = xrow[J+1];
      acc1[bi] = dot2f(w1.x, h1v.x, acc1[bi]);
      acc1[bi] = dot2f(w1.y, h1v.y, acc1[bi]);
      acc1[bi] = dot2f(w1.z, h1v.z, acc1[bi]);
      acc1[bi] = dot2f(w1.w, h1v.w, acc1[bi]);
    }
  }
  #pragma unroll
  for (int bi = 0; bi < 8; bi++)
    svx[(bq*8+bi)*RANK + r] = f16b(acc0[bi] + acc1[bi]);
  __syncthreads();

  const uint4* svx4 = (const uint4*)svx;
  float accb[BATCH];
  #pragma unroll 1
  for (int dd = 0; dd < 2; dd++) {
    int d = l + dd*512;
    const uint4* urow = (const uint4*)(ws32 + 196608 + d*64);
    #pragma unroll
    for (int bi = 0; bi < BATCH; bi++) accb[bi] = 0.f;
    #pragma unroll
    for (int RP = 0; RP < 16; RP++) {
      uint4 w = urow[RP];
      #pragma unroll
      for (int bi = 0; bi < BATCH; bi++) {
        uint4 sv = svx4[bi*16 + RP];
        accb[bi] = dot2f(w.x, sv.x, accb[bi]);
        accb[bi] = dot2f(w.y, sv.y, accb[bi]);
        accb[bi] = dot2f(w.z, sv.z, accb[bi]);
        accb[bi] = dot2f(w.w, sv.w, accb[bi]);
      }
    }
    float bv = bias[d];
    float* cslot = hout + (size_t)(t+1)*BD + d;
    #pragma unroll
    for (int bi = 0; bi < BATCH; bi++)
      cslot[(size_t)bi*DIM] = accb[bi] + bv;
  }
}

// ---------------------------------------------------------------------------
// K2: recurrence. One WG (256 threads, 1 CU) per batch element.
// v2 changes vs round 1:
//  - V_h LDS half stored interleaved VL4[J*256 + lane] so every wave's
//    ds_read_b128 is lane-contiguous (base + 16*lane) -> conflict-free.
//  - h stored in 4 LDS replicas (stride 520 words -> replica start banks
//    0/8/16/24); dpc group j reads replica j -> 4 broadcast streams on
//    disjoint bank quads -> conflict-free.
//  - c and z prefetched into registers at the top of each step.
//  - raw s_barrier + lgkmcnt(0) only (no vmcnt drain): global stores retire
//    asynchronously; no cross-lane global dependencies exist here.
// ---------------------------------------------------------------------------
__global__ __launch_bounds__(256, 1) void rec_kernel(
    const uint32_t* __restrict__ ws32, const float* __restrict__ z,
    float* __restrict__ outb) {
  const int b = blockIdx.x;
  const int l = threadIdx.x;
  float* hout = outb + TBD;
  const uint32_t* vhw = ws32;
  const uint32_t* uhw = ws32 + 65536;

  __shared__ __attribute__((aligned(16))) uint4    VL4[32*256];  // 128 KB
  __shared__ __attribute__((aligned(16))) uint32_t hrep[4*520];  // 8.3 KB
  __shared__ __attribute__((aligned(16))) uint32_t svh[64];      // 256 B

  const int rl  = l >> 2;   // 0..63
  const int dpc = l & 3;    // 0..3 : d-pair window [dpc*128, dpc*128+128)

  // V_h rows 0..63 -> LDS, interleaved: VL4[J*256 + l] = uint4 J of
  // (row rl, window dpc). Phase-A read addr = base + 16*l (gold pattern).
  {
    const uint4* src = (const uint4*)(vhw + rl*512 + dpc*128);
    #pragma unroll
    for (int J = 0; J < 32; J++) VL4[J*256 + l] = src[J];
  }
  // V_h rows 64..127 -> regs (128 words/lane)
  uint4 vq[32];
  {
    const uint4* src = (const uint4*)(vhw + (64 + rl)*512 + dpc*128);
    #pragma unroll
    for (int J = 0; J < 32; J++) vq[J] = src[J];
  }
  // U'_h rows d = l + 256k -> regs (256 words/lane)
  uint4 uq[4][16];
  #pragma unroll
  for (int k = 0; k < 4; k++) {
    const uint4* src = (const uint4*)(uhw + (l + 256*k)*64);
    #pragma unroll
    for (int J = 0; J < 16; J++) uq[k][J] = src[J];
  }
  // init h replicas from h-slot 0 (h0, written by prep_kernel)
  {
    const float2* h0p = (const float2*)(hout + b*DIM);
    for (int p = l; p < 512; p += 256) {
      uint32_t w = pack2(h0p[p].x, h0p[p].y);
      #pragma unroll
      for (int j = 0; j < 4; j++) hrep[j*520 + p] = w;
    }
  }
  __syncthreads();

  const float* zp = z + b*DIM;
  float*       cp = hout + BD + b*DIM;   // slot t+1 (holds c, overwritten with h)
  float*       op = outb + b*DIM;

  const uint4* hrow  = (const uint4*)(hrep + dpc*520) + dpc*32; // replica dpc, own window
  const uint4* svh4  = (const uint4*)svh;

  #pragma unroll 1
  for (int t = 0; t < T_STEPS; t++) {
    // ---- prefetch c (slot t+1) and z (slot t) for this step ----
    float cc0 = cp[l],       cc1 = cp[l+256],
          cc2 = cp[l+512],   cc3 = cp[l+768];
    float zz0 = zp[l],       zz1 = zp[l+256],
          zz2 = zp[l+512],   zz3 = zp[l+768];

    // ---- phase A: Vh partials over this lane's 128 d-pairs ----
    float aL0=0.f, aL1=0.f, aR0=0.f, aR1=0.f;
    #pragma unroll
    for (int J = 0; J < 32; J += 2) {
      uint4 hv0 = hrow[J];
      uint4 wl0 = VL4[J*256 + l];
      uint4 wr0 = vq[J];
      uint4 hv1 = hrow[J+1];
      uint4 wl1 = VL4[(J+1)*256 + l];
      uint4 wr1 = vq[J+1];
      aL0 = dot2f(wl0.x, hv0.x, aL0); aL0 = dot2f(wl0.y, hv0.y, aL0);
      aL0 = dot2f(wl0.z, hv0.z, aL0); aL0 = dot2f(wl0.w, hv0.w, aL0);
      aR0 = dot2f(wr0.x, hv0.x, aR0); aR0 = dot2f(wr0.y, hv0.y, aR0);
      aR0 = dot2f(wr0.z, hv0.z, aR0); aR0 = dot2f(wr0.w, hv0.w, aR0);
      aL1 = dot2f(wl1.x, hv1.x, aL1); aL1 = dot2f(wl1.y, hv1.y, aL1);
      aL1 = dot2f(wl1.z, hv1.z, aL1); aL1 = dot2f(wl1.w, hv1.w, aL1);
      aR1 = dot2f(wr1.x, hv1.x, aR1); aR1 = dot2f(wr1.y, hv1.y, aR1);
      aR1 = dot2f(wr1.z, hv1.z, aR1); aR1 = dot2f(wr1.w, hv1.w, aR1);
    }
    float aL = aL0 + aL1, aR = aR0 + aR1;
    aL += __shfl_xor(aL, 1); aL += __shfl_xor(aL, 2);
    aR += __shfl_xor(aR, 1); aR += __shfl_xor(aR, 2);
    if (dpc == 0) {
      ((uint16_t*)svh)[rl]      = f16b(aL);   // Vh[rl]
      ((uint16_t*)svh)[64 + rl] = f16b(aR);   // Vh[64+rl]
    }
    lds_barrier();

    // ---- phase B: Uh[d] for d = l+256k (RP-outer, broadcast sv reused x4) ----
    float a0[4] = {0.f,0.f,0.f,0.f};
    float a1[4] = {0.f,0.f,0.f,0.f};
    #pragma unroll
    for (int RP = 0; RP < 16; RP += 2) {
      uint4 sv0 = svh4[RP];
      uint4 sv1 = svh4[RP+1];
      #pragma unroll
      for (int k = 0; k < 4; k++) {
        uint4 w0 = uq[k][RP];
        uint4 w1 = uq[k][RP+1];
        a0[k] = dot2f(w0.x, sv0.x, a0[k]); a0[k] = dot2f(w0.y, sv0.y, a0[k]);
        a0[k] = dot2f(w0.z, sv0.z, a0[k]); a0[k] = dot2f(w0.w, sv0.w, a0[k]);
        a1[k] = dot2f(w1.x, sv1.x, a1[k]); a1[k] = dot2f(w1.y, sv1.y, a1[k]);
        a1[k] = dot2f(w1.z, sv1.z, a1[k]); a1[k] = dot2f(w1.w, sv1.w, a1[k]);
      }
    }
    float cc[4] = {cc0, cc1, cc2, cc3};
    float zz[4] = {zz0, zz1, zz2, zz3};
    #pragma unroll
    for (int k = 0; k < 4; k++) {
      int d = l + 256*k;
      float hv = fast_tanh(a0[k] + a1[k] + cc[k]);
      cp[d] = hv;                       // h[t+1] (f32, final output)
      uint16_t hb = f16b(hv);
      #pragma unroll
      for (int j = 0; j < 4; j++)
        ((uint16_t*)(hrep + j*520))[d] = hb;   // h for next step (f16 x4 replicas)
      op[d] = hv * fast_silu(zz[k]);    // out[t]
    }
    lds_barrier();

    cp += BD; zp += BD; op += BD;
  }
}

extern "C" void kernel_launch(void* const* d_in, const int* in_sizes, int n_in,
                              void* d_out, int out_size, void* d_ws, size_t ws_size,
                              hipStream_t stream) {
  const float* x  = (const float*)d_in[0];
  const float* z  = (const float*)d_in[1];
  const float* h0 = (const float*)d_in[2];
  const float* Uh = (const float*)d_in[3];
  const float* Vh = (const float*)d_in[4];
  const float* sh = (const float*)d_in[5];
  const float* Ux = (const float*)d_in[6];
  const float* Vx = (const float*)d_in[7];
  const float* sx = (const float*)d_in[8];
  const float* bb = (const float*)d_in[9];
  float* outb = (float*)d_out;
  uint32_t* ws32 = (uint32_t*)d_ws;   // needs 1 MiB

  prep_kernel<<<512, 256, 0, stream>>>(Uh, Vh, sh, Ux, Vx, sx, h0, ws32, outb + TBD);
  inp_kernel<<<T_STEPS, 512, 0, stream>>>(x, ws32, bb, outb + TBD);
  rec_kernel<<<BATCH, 256, 0, stream>>>(ws32, z, outb);
}

// Round 3
// 2545.898 us; speedup vs baseline: 3.4579x; 1.4132x over previous
//
#include <hip/hip_runtime.h>
#include <cstdint>

#define T_STEPS 1024
#define BATCH   32
#define DIM     1024
#define RANK    128
#define BD      (BATCH*DIM)            // 32768
#define TBD     ((size_t)T_STEPS*BD)   // 33554432

typedef _Float16 half2v __attribute__((ext_vector_type(2)));

__device__ __forceinline__ float dot2f(uint32_t a, uint32_t b, float acc) {
#if __has_builtin(__builtin_amdgcn_fdot2)
  return __builtin_amdgcn_fdot2(__builtin_bit_cast(half2v, a),
                                __builtin_bit_cast(half2v, b), acc, false);
#else
  half2v xx = __builtin_bit_cast(half2v, a);
  half2v yy = __builtin_bit_cast(half2v, b);
  return acc + (float)xx[0]*(float)yy[0] + (float)xx[1]*(float)yy[1];
#endif
}

__device__ __forceinline__ uint16_t f16b(float x) {
  _Float16 h = (_Float16)x;
  return __builtin_bit_cast(unsigned short, h);
}
__device__ __forceinline__ uint32_t pack2(float a, float b) {
  return (uint32_t)f16b(a) | ((uint32_t)f16b(b) << 16);
}
__device__ __forceinline__ float fast_tanh(float x) {
  float e = __expf(2.0f*x);
  return 1.0f - 2.0f/(e + 1.0f);
}
__device__ __forceinline__ float fast_silu(float zz) {
  return zz / (1.0f + __expf(-zz));
}

// barrier that does NOT drain vmcnt: only LDS ordering is required between
// phases (no cross-lane global-memory dependencies exist in rec_kernel).
__device__ __forceinline__ void lds_barrier() {
  asm volatile("s_waitcnt lgkmcnt(0)" ::: "memory");
  __builtin_amdgcn_s_barrier();
  __builtin_amdgcn_sched_barrier(0);
}

// ---------------------------------------------------------------------------
// K0: pack weights to f16 pairs in ws (s folded into U), h0 -> h-slot 0.
// ws layout (uint32 words):
//   [0]      vhw  [128][512]  V_h f16 pairs (d-major pairs)
//   [65536]  uhw2 [1024][64]  U'_h with INTERLEAVED column pairs:
//                             word k of row d = pack(U[d][k]*s[k], U[d][k+64]*s[k+64])
//   [131072] vxw  [128][512]
//   [196608] uxw  [1024][64]  (plain pair layout, used by inp_kernel)
// ---------------------------------------------------------------------------
__global__ void prep_kernel(const float* __restrict__ Uh, const float* __restrict__ Vh,
                            const float* __restrict__ sh, const float* __restrict__ Ux,
                            const float* __restrict__ Vx, const float* __restrict__ sx,
                            const float* __restrict__ h0, uint32_t* __restrict__ ws32,
                            float* __restrict__ hout) {
  int i = blockIdx.x*blockDim.x + threadIdx.x;
  int n = gridDim.x*blockDim.x;
  for (int p = i; p < 65536; p += n) {
    int r = p >> 9, dp = p & 511;
    ws32[p] = pack2(Vh[r*1024 + 2*dp], Vh[r*1024 + 2*dp + 1]);
  }
  for (int p = i; p < 65536; p += n) {
    int d = p >> 6, k = p & 63;
    ws32[65536 + p] = pack2(Uh[d*128 + k]      * sh[k],
                            Uh[d*128 + 64 + k] * sh[64 + k]);
  }
  for (int p = i; p < 65536; p += n) {
    int r = p >> 9, dp = p & 511;
    ws32[131072 + p] = pack2(Vx[r*1024 + 2*dp], Vx[r*1024 + 2*dp + 1]);
  }
  for (int p = i; p < 65536; p += n) {
    int d = p >> 6, rp = p & 63;
    ws32[196608 + p] = pack2(Ux[d*128 + 2*rp]   * sx[2*rp],
                             Ux[d*128 + 2*rp+1] * sx[2*rp+1]);
  }
  for (int p = i; p < BD; p += n) hout[p] = h0[p];
}

// ---------------------------------------------------------------------------
// K1: input branch. One WG per timestep t. (unchanged)
// ---------------------------------------------------------------------------
__global__ __launch_bounds__(512, 4) void inp_kernel(
    const float* __restrict__ x, const uint32_t* __restrict__ ws32,
    const float* __restrict__ bias, float* __restrict__ hout) {
  const int t = blockIdx.x;
  const int l = threadIdx.x;  // 0..511
  __shared__ __attribute__((aligned(16))) uint32_t xs[32*516];
  __shared__ __attribute__((aligned(16))) uint16_t svx[BATCH*RANK];

  const float4* xg = (const float4*)(x + (size_t)t*BD);
  #pragma unroll
  for (int k = 0; k < 16; k++) {
    int i = l + 512*k;
    float4 v = xg[i];
    int bb = i >> 8;
    int d4 = i & 255;
    xs[bb*516 + d4*2]     = pack2(v.x, v.y);
    xs[bb*516 + d4*2 + 1] = pack2(v.z, v.w);
  }
  __syncthreads();

  const int r  = l & 127;
  const int bq = l >> 7;
  const uint4* wrow = (const uint4*)(ws32 + 131072 + r*512);
  float acc0[8], acc1[8];
  #pragma unroll
  for (int bi = 0; bi < 8; bi++) { acc0[bi] = 0.f; acc1[bi] = 0.f; }
  #pragma unroll 4
  for (int J = 0; J < 128; J += 2) {
    uint4 w0 = wrow[J];
    uint4 w1 = wrow[J+1];
    #pragma unroll
    for (int bi = 0; bi < 8; bi++) {
      const uint4* xrow = (const uint4*)(xs + (bq*8+bi)*516);
      uint4 h0v = xrow[J];
      acc0[bi] = dot2f(w0.x, h0v.x, acc0[bi]);
      acc0[bi] = dot2f(w0.y, h0v.y, acc0[bi]);
      acc0[bi] = dot2f(w0.z, h0v.z, acc0[bi]);
      acc0[bi] = dot2f(w0.w, h0v.w, acc0[bi]);
      uint4 h1v = xrow[J+1];
      acc1[bi] = dot2f(w1.x, h1v.x, acc1[bi]);
      acc1[bi] = dot2f(w1.y, h1v.y, acc1[bi]);
      acc1[bi] = dot2f(w1.z, h1v.z, acc1[bi]);
      acc1[bi] = dot2f(w1.w, h1v.w, acc1[bi]);
    }
  }
  #pragma unroll
  for (int bi = 0; bi < 8; bi++)
    svx[(bq*8+bi)*RANK + r] = f16b(acc0[bi] + acc1[bi]);
  __syncthreads();

  const uint4* svx4 = (const uint4*)svx;
  float accb[BATCH];
  #pragma unroll 1
  for (int dd = 0; dd < 2; dd++) {
    int d = l + dd*512;
    const uint4* urow = (const uint4*)(ws32 + 196608 + d*64);
    #pragma unroll
    for (int bi = 0; bi < BATCH; bi++) accb[bi] = 0.f;
    #pragma unroll
    for (int RP = 0; RP < 16; RP++) {
      uint4 w = urow[RP];
      #pragma unroll
      for (int bi = 0; bi < BATCH; bi++) {
        uint4 sv = svx4[bi*16 + RP];
        accb[bi] = dot2f(w.x, sv.x, accb[bi]);
        accb[bi] = dot2f(w.y, sv.y, accb[bi]);
        accb[bi] = dot2f(w.z, sv.z, accb[bi]);
        accb[bi] = dot2f(w.w, sv.w, accb[bi]);
      }
    }
    float bv = bias[d];
    float* cslot = hout + (size_t)(t+1)*BD + d;
    #pragma unroll
    for (int bi = 0; bi < BATCH; bi++)
      cslot[(size_t)bi*DIM] = accb[bi] + bv;
  }
}

// ---------------------------------------------------------------------------
// K2: recurrence. One WG (512 threads = 8 waves, 2 waves/SIMD) per batch b.
// v3 changes vs round 2:
//  - 512 threads: per-lane weight regs 384 -> 192 words (vq 64 + uq 128)
//    so 2 waves/SIMD fit -> latency hiding for LDS/global/barrier stalls.
//  - lane l: group g=l>>3 owns V_h rows {g (LDS), g+64 (regs)}; window
//    j=l&7 covers d-pairs [64j,64j+64). 8-lane shfl_xor(1,2,4) reduce.
//  - U'_h columns pre-interleaved (pairs k,k+64) so svh is packed u32 pairs.
//  - h in 8 staggered LDS replicas (stride 516 words): broadcast stream j
//    starts at bank 4(j+J) -> 8 disjoint bank quads, conflict-free.
//  - all global / h accesses are adjacent-pair (float2 / b32).
// ---------------------------------------------------------------------------
__global__ __launch_bounds__(512, 2) void rec_kernel(
    const uint32_t* __restrict__ ws32, const float* __restrict__ z,
    float* __restrict__ outb) {
  const int b = blockIdx.x;
  const int l = threadIdx.x;   // 0..511
  const int g = l >> 3;        // 0..63
  const int j = l & 7;         // d-window
  float* hout = outb + TBD;
  const uint32_t* vhw = ws32;
  const uint32_t* uhw = ws32 + 65536;

  __shared__ __attribute__((aligned(16))) uint4    VL4[16*512];  // 128 KB
  __shared__ __attribute__((aligned(16))) uint32_t hrep[8*516];  // 16.5 KB
  __shared__ __attribute__((aligned(16))) uint32_t svh[64];      // 256 B

  // stage V_h rows 0..63 interleaved: VL4[J*512 + l] = uint4 J of (row g, win j)
  {
    const uint4* src = (const uint4*)(vhw + g*512 + j*64);
    #pragma unroll
    for (int J = 0; J < 16; J++) VL4[J*512 + l] = src[J];
  }
  // V_h row 64+g, window j -> regs (64 words)
  uint4 vq[16];
  {
    const uint4* src = (const uint4*)(vhw + (64 + g)*512 + j*64);
    #pragma unroll
    for (int J = 0; J < 16; J++) vq[J] = src[J];
  }
  // U'_h rows 2l, 2l+1 (interleaved cols) -> regs (128 words)
  uint4 uq0[16], uq1[16];
  {
    const uint4* s0 = (const uint4*)(uhw + (2*l)*64);
    const uint4* s1 = (const uint4*)(uhw + (2*l+1)*64);
    #pragma unroll
    for (int J = 0; J < 16; J++) { uq0[J] = s0[J]; uq1[J] = s1[J]; }
  }
  // init h replicas from h-slot 0 (h0)
  {
    const float2 v = ((const float2*)(hout + b*DIM))[l];
    uint32_t w = pack2(v.x, v.y);
    #pragma unroll
    for (int r = 0; r < 8; r++) hrep[r*516 + l] = w;
  }
  __syncthreads();

  const float2* zp2 = (const float2*)(z + b*DIM) + l;
  float2*       cp2 = (float2*)(hout + BD + b*DIM) + l;  // slot t+1: c -> h
  float2*       op2 = (float2*)(outb + b*DIM) + l;

  const uint4* hrow = (const uint4*)(hrep + j*516) + j*16;  // replica j, own window
  const uint4* svh4 = (const uint4*)svh;

  #pragma unroll 1
  for (int t = 0; t < T_STEPS; t++) {
    // prefetch c (slot t+1) and z (slot t)
    float2 cc = *cp2;
    float2 zz = *zp2;

    // ---- phase A: rows g (LDS) and 64+g (regs) over window j ----
    float aL0=0.f, aL1=0.f, aR0=0.f, aR1=0.f;
    #pragma unroll
    for (int J = 0; J < 16; J += 2) {
      uint4 hv0 = hrow[J];
      uint4 wl0 = VL4[J*512 + l];
      uint4 wr0 = vq[J];
      uint4 hv1 = hrow[J+1];
      uint4 wl1 = VL4[(J+1)*512 + l];
      uint4 wr1 = vq[J+1];
      aL0 = dot2f(wl0.x, hv0.x, aL0); aL0 = dot2f(wl0.y, hv0.y, aL0);
      aL0 = dot2f(wl0.z, hv0.z, aL0); aL0 = dot2f(wl0.w, hv0.w, aL0);
      aR0 = dot2f(wr0.x, hv0.x, aR0); aR0 = dot2f(wr0.y, hv0.y, aR0);
      aR0 = dot2f(wr0.z, hv0.z, aR0); aR0 = dot2f(wr0.w, hv0.w, aR0);
      aL1 = dot2f(wl1.x, hv1.x, aL1); aL1 = dot2f(wl1.y, hv1.y, aL1);
      aL1 = dot2f(wl1.z, hv1.z, aL1); aL1 = dot2f(wl1.w, hv1.w, aL1);
      aR1 = dot2f(wr1.x, hv1.x, aR1); aR1 = dot2f(wr1.y, hv1.y, aR1);
      aR1 = dot2f(wr1.z, hv1.z, aR1); aR1 = dot2f(wr1.w, hv1.w, aR1);
    }
    float aL = aL0 + aL1, aR = aR0 + aR1;
    aL += __shfl_xor(aL, 1); aL += __shfl_xor(aL, 2); aL += __shfl_xor(aL, 4);
    aR += __shfl_xor(aR, 1); aR += __shfl_xor(aR, 2); aR += __shfl_xor(aR, 4);
    if (j == 0) svh[g] = pack2(aL, aR);   // {Vh[g], Vh[g+64]} packed
    lds_barrier();

    // ---- phase B: d0=2l, d1=2l+1 over packed svh pairs ----
    float p00=0.f, p01=0.f, p10=0.f, p11=0.f;
    #pragma unroll
    for (int RP = 0; RP < 16; RP += 2) {
      uint4 sv0 = svh4[RP];
      uint4 sv1 = svh4[RP+1];
      uint4 w00 = uq0[RP], w01 = uq0[RP+1];
      uint4 w10 = uq1[RP], w11 = uq1[RP+1];
      p00 = dot2f(w00.x, sv0.x, p00); p00 = dot2f(w00.y, sv0.y, p00);
      p00 = dot2f(w00.z, sv0.z, p00); p00 = dot2f(w00.w, sv0.w, p00);
      p01 = dot2f(w01.x, sv1.x, p01); p01 = dot2f(w01.y, sv1.y, p01);
      p01 = dot2f(w01.z, sv1.z, p01); p01 = dot2f(w01.w, sv1.w, p01);
      p10 = dot2f(w10.x, sv0.x, p10); p10 = dot2f(w10.y, sv0.y, p10);
      p10 = dot2f(w10.z, sv0.z, p10); p10 = dot2f(w10.w, sv0.w, p10);
      p11 = dot2f(w11.x, sv1.x, p11); p11 = dot2f(w11.y, sv1.y, p11);
      p11 = dot2f(w11.z, sv1.z, p11); p11 = dot2f(w11.w, sv1.w, p11);
    }
    float hv0 = fast_tanh(p00 + p01 + cc.x);
    float hv1 = fast_tanh(p10 + p11 + cc.y);
    *cp2 = make_float2(hv0, hv1);                    // h[t+1] (f32 output)
    uint32_t w = pack2(hv0, hv1);
    #pragma unroll
    for (int r = 0; r < 8; r++) hrep[r*516 + l] = w; // h for next step
    *op2 = make_float2(hv0 * fast_silu(zz.x), hv1 * fast_silu(zz.y));
    lds_barrier();

    cp2 += BD/2; zp2 += BD/2; op2 += BD/2;
  }
}

extern "C" void kernel_launch(void* const* d_in, const int* in_sizes, int n_in,
                              void* d_out, int out_size, void* d_ws, size_t ws_size,
                              hipStream_t stream) {
  const float* x  = (const float*)d_in[0];
  const float* z  = (const float*)d_in[1];
  const float* h0 = (const float*)d_in[2];
  const float* Uh = (const float*)d_in[3];
  const float* Vh = (const float*)d_in[4];
  const float* sh = (const float*)d_in[5];
  const float* Ux = (const float*)d_in[6];
  const float* Vx = (const float*)d_in[7];
  const float* sx = (const float*)d_in[8];
  const float* bb = (const float*)d_in[9];
  float* outb = (float*)d_out;
  uint32_t* ws32 = (uint32_t*)d_ws;   // needs 1 MiB

  prep_kernel<<<512, 256, 0, stream>>>(Uh, Vh, sh, Ux, Vx, sx, h0, ws32, outb + TBD);
  inp_kernel<<<T_STEPS, 512, 0, stream>>>(x, ws32, bb, outb + TBD);
  rec_kernel<<<BATCH, 512, 0, stream>>>(ws32, z, outb);
}